// Round 1
// baseline (275.984 us; speedup 1.0000x reference)
//
#include <hip/hip_runtime.h>
#include <hip/hip_bf16.h>

typedef unsigned short u16;
typedef unsigned int u32;
typedef __attribute__((ext_vector_type(8))) __bf16 bf16x8;
typedef __attribute__((ext_vector_type(4))) float f32x4;
typedef __attribute__((ext_vector_type(4))) u16 u16x4;

#define LQ 1000   // sequence length
#define MM 8000   // B*L tokens
// D=1024, H=16, HD=64, BH=128

__device__ __forceinline__ u16 f2bf(float f){
  __bf16 h = (__bf16)f;
  return __builtin_bit_cast(u16, h);
}
// async global->LDS, 16B per lane; LDS dest = wave-uniform base + lane*16 (m104/m108)
__device__ __forceinline__ void async_copy16(const void* g, void* l){
  __builtin_amdgcn_global_load_lds((const __attribute__((address_space(1))) u32*)g,
                                   (__attribute__((address_space(3))) u32*)l, 16, 0, 0);
}

// ---------------- fp32 -> bf16 convert (4 elems/thread) ----------------
__global__ __launch_bounds__(256)
void kcvt(const float* __restrict__ src, u16* __restrict__ dst, long n){
  const long i = ((long)blockIdx.x * 256 + threadIdx.x) * 4;
  if (i + 3 >= n) {
    for (long j = i; j < n; j++) dst[j] = f2bf(src[j]);
    return;
  }
  const float4 v = *(const float4*)&src[i];
  u16x4 o; o.x = f2bf(v.x); o.y = f2bf(v.y); o.z = f2bf(v.z); o.w = f2bf(v.w);
  *(u16x4*)&dst[i] = o;
}

// ---------------- fp32 read, transpose, bf16 write; 32x32 tiles ----------------
__global__ __launch_bounds__(256)
void ktranspose_cvt(const float* __restrict__ src, u16* __restrict__ dst, int R, int C){
  __shared__ u16 tile[32][33];
  const int tx = threadIdx.x & 31, ty = threadIdx.x >> 5;   // 32 x 8
  const long bx = (long)blockIdx.x * 32, by = (long)blockIdx.y * 32;
  #pragma unroll
  for (int i = 0; i < 32; i += 8) tile[ty + i][tx] = f2bf(src[(by + ty + i) * C + bx + tx]);
  __syncthreads();
  #pragma unroll
  for (int i = 0; i < 32; i += 8) dst[(bx + ty + i) * R + by + tx] = tile[tx][ty + i];
}

// ---------------- gemm256: 256x256 tile, BK=32, 8 waves (2Mx4N), 4-deep LDS pipeline ----------
// T-stack port (plain HIP): T1 XCD swizzle, T2 granule XOR-swizzle (both-sides, rule 21),
// T3/T4 counted vmcnt (never 0 in steady state), T5 setprio around MFMA clusters.
// Race-freedom by construction: 4 LDS buffers, tile T_{j+3} staged in iter j targets buf[(j+3)&3],
// whose previous tenant T_{j-1} was read in iter j-1; an lgkmcnt(0)+s_barrier separates all reads
// of a buffer from the issue of the stores that overwrite it (mod-4 distance >= 1 full iteration).
// LDS: 4 bufs x (A 256x32 bf16 = 16KB | B 256x32 = 16KB) = 128KB dynamic.
// EPI==0: scatter bf16 into Q [BH,L,64], K [BH,L,64], VT [BH,64,L]
// EPI==1: OF[m*1024 + n] = fp32(acc + bias)
template<int EPI>
__global__ __launch_bounds__(512, 2)
void gemm256(const u16* __restrict__ A, const u16* __restrict__ BT, const float* __restrict__ bias,
             u16* __restrict__ O0, u16* __restrict__ O1, u16* __restrict__ O2,
             float* __restrict__ OF)
{
  constexpr int K = 1024;
  constexpr int NT = K / 32;               // 32 K-tiles
  extern __shared__ __align__(16) char lds[];
  const int t = threadIdx.x, lane = t & 63, wave = t >> 6;
  const int quad = lane >> 4, l15 = lane & 15;

  // T1: XCD-aware bijective swizzle (nwg % 8 == 0 for both grids: 384, 128)
  const int nwgx = gridDim.x;
  const int nwg = nwgx * gridDim.y;
  int bid = blockIdx.y * nwgx + blockIdx.x;
  bid = (bid & 7) * (nwg >> 3) + (bid >> 3);
  const int m0 = (bid / nwgx) * 256, n0 = (bid % nwgx) * 256;

  const int wm = (wave >> 2) * 128, wn = (wave & 3) * 64;

  // ---- staging source offsets (per-thread invariant; inverse T2 swizzle on global source) ----
  // wave's two 1KB segments per matrix: seg s=wave (rows s*16..+15) and s=wave+8 (rows +128)
  const int srow  = wave * 16 + (lane >> 2);
  const int scolg = (lane & 3) ^ ((srow >> 1) & 3);     // phys granule c' holds logical c'^((row>>1)&3)
  const long aofs0 = (long)min(m0 + srow,       MM - 1) * K + scolg * 8;
  const long aofs1 = (long)min(m0 + srow + 128, MM - 1) * K + scolg * 8;
  const long bofs0 = (long)(n0 + srow)       * K + scolg * 8;
  const long bofs1 = (long)(n0 + srow + 128) * K + scolg * 8;

  // ---- ds_read byte offsets (loop-invariant; T2 swizzle on read side) ----
  const int swz = (l15 >> 1) & 3;                        // row = 16*c + l15 -> (row>>1)&3 == (l15>>1)&3
  int aoff[8], boff[4];
  #pragma unroll
  for (int m = 0; m < 8; m++) aoff[m] = (wm + m * 16 + l15) * 64 + ((quad ^ swz) << 4);
  #pragma unroll
  for (int n = 0; n < 4; n++) boff[n] = 16384 + (wn + n * 16 + l15) * 64 + ((quad ^ swz) << 4);

  f32x4 acc[8][4] = {};

  auto STAGE_A = [&](int j){
    char* d = lds + (j & 3) * 32768 + wave * 1024;
    const long kt = (long)j * 32;
    async_copy16(A + aofs0 + kt, d);
    async_copy16(A + aofs1 + kt, d + 8192);
  };
  auto STAGE_B = [&](int j){
    char* d = lds + (j & 3) * 32768 + 16384 + wave * 1024;
    const long kt = (long)j * 32;
    async_copy16(BT + bofs0 + kt, d);
    async_copy16(BT + bofs1 + kt, d + 8192);
  };

  // prologue: prefetch T0,T1,T2 (12 loads/wave in flight)
  STAGE_A(0); STAGE_B(0);
  STAGE_A(1); STAGE_B(1);
  STAGE_A(2); STAGE_B(2);

  for (int j = 0; j < NT; ++j) {
    // T4: counted vmcnt — in steady state 2 tiles (8 loads) stay in flight across the barrier
    if (j < NT - 2)       asm volatile("s_waitcnt vmcnt(8)" ::: "memory");
    else if (j == NT - 2) asm volatile("s_waitcnt vmcnt(4)" ::: "memory");
    else                  asm volatile("s_waitcnt vmcnt(0)" ::: "memory");
    __builtin_amdgcn_s_barrier();                       // raw barrier: no vmcnt drain

    char* buf = lds + (j & 3) * 32768;
    bf16x8 bfr[4], afr[4];
    #pragma unroll
    for (int n = 0; n < 4; n++) bfr[n] = *(const bf16x8*)(buf + boff[n]);
    #pragma unroll
    for (int m = 0; m < 4; m++) afr[m] = *(const bf16x8*)(buf + aoff[m]);
    if (j < NT - 3) STAGE_A(j + 3);

    __builtin_amdgcn_s_setprio(1);                      // T5
    #pragma unroll
    for (int m = 0; m < 4; m++)
      #pragma unroll
      for (int n = 0; n < 4; n++)
        acc[m][n] = __builtin_amdgcn_mfma_f32_16x16x32_bf16(afr[m], bfr[n], acc[m][n], 0, 0, 0);
    __builtin_amdgcn_s_setprio(0);
    __builtin_amdgcn_s_barrier();                       // mid barrier: phase-lock slot1/slot2

    #pragma unroll
    for (int m = 0; m < 4; m++) afr[m] = *(const bf16x8*)(buf + aoff[m + 4]);
    if (j < NT - 3) STAGE_B(j + 3);

    __builtin_amdgcn_s_setprio(1);
    #pragma unroll
    for (int m = 0; m < 4; m++)
      #pragma unroll
      for (int n = 0; n < 4; n++)
        acc[m + 4][n] = __builtin_amdgcn_mfma_f32_16x16x32_bf16(afr[m], bfr[n], acc[m + 4][n], 0, 0, 0);
    __builtin_amdgcn_s_setprio(0);

    // Drain ds_reads of buf[j&3] before the loop-top barrier: next iteration's STAGE_A(j+4)
    // overwrites this buffer, and its issue is fenced behind that barrier (WAR-safe).
    asm volatile("s_waitcnt lgkmcnt(0)" ::: "memory");
  }

  // ---------------- epilogue ----------------
  float bs[4]; int cols[4];
  #pragma unroll
  for (int n = 0; n < 4; n++) { cols[n] = n0 + wn + n * 16 + l15; bs[n] = bias[cols[n]]; }

  #pragma unroll
  for (int m = 0; m < 8; m++) {
    #pragma unroll
    for (int r = 0; r < 4; r++) {
      const int row = m0 + wm + m * 16 + quad * 4 + r;  // C/D: row = quad*4+reg, col = lane&15 (m89)
      if (row >= MM) continue;
      if (EPI == 0) {
        const int b = row / 1000, l = row - b * 1000;
        #pragma unroll
        for (int n = 0; n < 4; n++) {
          const u16 o = f2bf(acc[m][n][r] + bs[n]);
          const int col = cols[n];
          const int which = col >> 10, hh = (col >> 6) & 15, dd = col & 63;
          const int bh = b * 16 + hh;
          if      (which == 0) O0[((long)bh * LQ + l) * 64 + dd] = o;
          else if (which == 1) O1[((long)bh * LQ + l) * 64 + dd] = o;
          else                 O2[((long)bh * 64 + dd) * LQ + l] = o;   // V stored transposed per head
        }
      } else {
        #pragma unroll
        for (int n = 0; n < 4; n++)
          OF[(long)row * 1024 + cols[n]] = acc[m][n][r] + bs[n];        // fp32 store
      }
    }
  }
}

// ---------------- flash attention v4: balanced pairing + register prefetch (r9, validated) ----------
__global__ __launch_bounds__(256)
void attn_kernel(const u16* __restrict__ Qb, const u16* __restrict__ Kb,
                 const u16* __restrict__ VTb, u16* __restrict__ AO)
{
  __shared__ __align__(16) u16 Ps[4][2][16 * 40];   // [wave][qblock][q=16][key=32 +8 pad]
  const int t = threadIdx.x, lane = t & 63, wave = t >> 6;
  const int quad = lane >> 4, l15 = lane & 15;
  const int bh = blockIdx.y;
  const int c = blockIdx.x * 4 + wave;              // 0..15 (grid.x = 4)
  const u16* Q  = Qb  + (long)bh * LQ * 64;
  const u16* Kp = Kb  + (long)bh * LQ * 64;
  const u16* VT = VTb + (long)bh * 64 * LQ;
  const int b = bh >> 4, h = bh & 15;
  const float sscale = 0.18033688011112042f;        // (1/sqrt(64)) * log2(e)

  for (int pass = 0; pass < 2; ++pass) {
    const int chunk = pass ? (31 - c) : c;          // pass0: 0..15, pass1: 16..31
    const int qbase = chunk * 32;
    const int nkt = chunk + 1;

    // Q B-frags for the two 16-col q-blocks: B[k=d=quad*8+j][n=q=l15]
    int qv[2]; bf16x8 bq0[2], bq1[2];
    #pragma unroll
    for (int g = 0; g < 2; g++) {
      qv[g] = qbase + g * 16 + l15;
      const int qc = min(qv[g], LQ - 1);
      bq0[g] = *(const bf16x8*)&Q[(long)qc * 64 +      quad * 8];
      bq1[g] = *(const bf16x8*)&Q[(long)qc * 64 + 32 + quad * 8];
    }

    float l_p[2] = { 0.f, 0.f };
    f32x4 o[2][4] = {};

    // prefetch tile 0
    bf16x8 pa00, pa01, pa10, pa11, pav0, pav1, pav2, pav3;
    {
      const int krA = min(l15, LQ - 1), krB = min(16 + l15, LQ - 1);
      pa00 = *(const bf16x8*)&Kp[(long)krA * 64 +      quad * 8];
      pa01 = *(const bf16x8*)&Kp[(long)krA * 64 + 32 + quad * 8];
      pa10 = *(const bf16x8*)&Kp[(long)krB * 64 +      quad * 8];
      pa11 = *(const bf16x8*)&Kp[(long)krB * 64 + 32 + quad * 8];
      const int vcol = min(quad * 8, LQ - 8);
      pav0 = *(const bf16x8*)&VT[(long)( 0 + l15) * LQ + vcol];
      pav1 = *(const bf16x8*)&VT[(long)(16 + l15) * LQ + vcol];
      pav2 = *(const bf16x8*)&VT[(long)(32 + l15) * LQ + vcol];
      pav3 = *(const bf16x8*)&VT[(long)(48 + l15) * LQ + vcol];
    }

    for (int kk = 0; kk < nkt; ++kk) {
      const int k0 = kk * 32;
      const bool lastt = (kk + 1 == nkt);           // wave-uniform
      const bf16x8 a00 = pa00, a01 = pa01, a10 = pa10, a11 = pa11;
      bf16x8 av[4] = { pav0, pav1, pav2, pav3 };
      if (!lastt) {                                 // issue next tile's loads early
        const int n0k = k0 + 32;
        const int krA = min(n0k + l15, LQ - 1), krB = min(n0k + 16 + l15, LQ - 1);
        pa00 = *(const bf16x8*)&Kp[(long)krA * 64 +      quad * 8];
        pa01 = *(const bf16x8*)&Kp[(long)krA * 64 + 32 + quad * 8];
        pa10 = *(const bf16x8*)&Kp[(long)krB * 64 +      quad * 8];
        pa11 = *(const bf16x8*)&Kp[(long)krB * 64 + 32 + quad * 8];
        const int vcol = min(n0k + quad * 8, LQ - 8);
        pav0 = *(const bf16x8*)&VT[(long)( 0 + l15) * LQ + vcol];
        pav1 = *(const bf16x8*)&VT[(long)(16 + l15) * LQ + vcol];
        pav2 = *(const bf16x8*)&VT[(long)(32 + l15) * LQ + vcol];
        pav3 = *(const bf16x8*)&VT[(long)(48 + l15) * LQ + vcol];
      }

      #pragma unroll
      for (int g = 0; g < 2; g++) {
        const f32x4 z = {};
        f32x4 s0 = __builtin_amdgcn_mfma_f32_16x16x32_bf16(a00, bq0[g], z, 0, 0, 0);
        s0       = __builtin_amdgcn_mfma_f32_16x16x32_bf16(a01, bq1[g], s0, 0, 0, 0);
        f32x4 s1 = __builtin_amdgcn_mfma_f32_16x16x32_bf16(a10, bq0[g], z, 0, 0, 0);
        s1       = __builtin_amdgcn_mfma_f32_16x16x32_bf16(a11, bq1[g], s1, 0, 0, 0);

        float p0[4], p1[4];
        if (lastt) {                                // only masked tile (k0 == qbase)
          const int q = qv[g];
          #pragma unroll
          for (int r = 0; r < 4; r++) {
            const int key0 = k0 + quad * 4 + r;     // S^T row = key (m89)
            p0[r] = __builtin_amdgcn_exp2f((key0      <= q) ? s0[r] * sscale : -3.0e38f);
            p1[r] = __builtin_amdgcn_exp2f((key0 + 16 <= q) ? s1[r] * sscale : -3.0e38f);
          }
        } else {
          #pragma unroll
          for (int r = 0; r < 4; r++) {
            p0[r] = __builtin_amdgcn_exp2f(s0[r] * sscale);
            p1[r] = __builtin_amdgcn_exp2f(s1[r] * sscale);
          }
        }
        u16x4 w0, w1; float ls = 0.f;
        #pragma unroll
        for (int r = 0; r < 4; r++) {
          w0[r] = f2bf(p0[r]); w1[r] = f2bf(p1[r]);
          ls += p0[r] + p1[r];
        }
        l_p[g] += ls;
        // P[q][key] -> per-wave LDS (same-wave write->read, proven safe rounds 2-9)
        *(u16x4*)&Ps[wave][g][l15 * 40 + quad * 4]      = w0;
        *(u16x4*)&Ps[wave][g][l15 * 40 + 16 + quad * 4] = w1;
        // B-frag of P^T: B[k=key=quad*8+j][n=q=l15]
        const bf16x8 bp = *(const bf16x8*)&Ps[wave][g][l15 * 40 + quad * 8];
        #pragma unroll
        for (int cc = 0; cc < 4; cc++)
          o[g][cc] = __builtin_amdgcn_mfma_f32_16x16x32_bf16(av[cc], bp, o[g][cc], 0, 0, 0);
      }
    }

    #pragma unroll
    for (int g = 0; g < 2; g++) {
      if (qv[g] >= LQ) continue;
      float l = l_p[g];                             // cross-quad reduce once per chunk
      l += __shfl_xor(l, 16);
      l += __shfl_xor(l, 32);
      const float inv = 1.0f / l;
      const long base = ((long)(b * LQ + qv[g])) * 1024 + h * 64;
      #pragma unroll
      for (int cc = 0; cc < 4; cc++) {              // O^T: row d = cc*16+quad*4+r, col q
        u16x4 w;
        #pragma unroll
        for (int r = 0; r < 4; r++) w[r] = f2bf(o[g][cc][r] * inv);
        *(u16x4*)&AO[base + cc * 16 + quad * 4] = w; // 8B store, d-contiguous
      }
    }
  }
}

// ---------------- launcher ----------------
extern "C" void kernel_launch(void* const* d_in, const int* in_sizes, int n_in,
                              void* d_out, int out_size, void* d_ws, size_t ws_size,
                              hipStream_t stream) {
  const float* x    = (const float*)d_in[0];   // [8,1000,1024] fp32
  const float* Wqkv = (const float*)d_in[1];   // [1024,3072]  fp32
  const float* bqkv = (const float*)d_in[2];   // [3072]       fp32
  const float* Wo   = (const float*)d_in[3];   // [1024,1024]  fp32
  const float* bo   = (const float*)d_in[4];   // [1024]       fp32
  float* out = (float*)d_out;                  // [8,1000,1024] fp32

  char* ws = (char*)d_ws;                      // validated layout (rounds 2-9)
  u16* WqkvT = (u16*)(ws);                                   // 3072*1024*2 = 6291456
  u16* WoT   = (u16*)(ws + 6291456);                         // 1024*1024*2 = 2097152
  u16* xb    = (u16*)(ws + 8388608);                         // 8000*1024*2 = 16384000
  u16* Qb    = (u16*)(ws + 8388608 + 16384000L);             // 128*1000*64*2
  u16* Kb    = (u16*)(ws + 8388608 + 2 * 16384000L);
  u16* VTb   = (u16*)(ws + 8388608 + 3 * 16384000L);
  u16* AO    = xb;   // reuse: x fully consumed by gemm<0> before attn writes AO

  static bool inited = false;                  // allow 128KB dynamic LDS (one-time, not stream-ordered)
  if (!inited) {
    (void)hipFuncSetAttribute(reinterpret_cast<const void*>(&gemm256<0>),
                              hipFuncAttributeMaxDynamicSharedMemorySize, 131072);
    (void)hipFuncSetAttribute(reinterpret_cast<const void*>(&gemm256<1>),
                              hipFuncAttributeMaxDynamicSharedMemorySize, 131072);
    inited = true;
  }

  kcvt<<<8000, 256, 0, stream>>>(x, xb, 8192000L);
  ktranspose_cvt<<<dim3(96, 32), 256, 0, stream>>>(Wqkv, WqkvT, 1024, 3072);
  ktranspose_cvt<<<dim3(32, 32), 256, 0, stream>>>(Wo,   WoT,   1024, 1024);
  gemm256<0><<<dim3(12, 32), 512, 131072, stream>>>(xb, WqkvT, bqkv, Qb, Kb, VTb, nullptr);
  attn_kernel<<<dim3(4, 128), 256, 0, stream>>>(Qb, Kb, VTb, AO);
  gemm256<1><<<dim3(4, 32), 512, 131072, stream>>>(AO, WoT, bo, nullptr, nullptr, nullptr, out);
}

// Round 2
// 270.831 us; speedup vs baseline: 1.0190x; 1.0190x over previous
//
#include <hip/hip_runtime.h>
#include <hip/hip_bf16.h>

typedef unsigned short u16;
typedef unsigned int u32;
typedef __attribute__((ext_vector_type(8))) __bf16 bf16x8;
typedef __attribute__((ext_vector_type(4))) float f32x4;
typedef __attribute__((ext_vector_type(4))) u16 u16x4;

#define LQ 1000   // sequence length
#define MM 8000   // B*L tokens
// D=1024, H=16, HD=64, BH=128

__device__ __forceinline__ u16 f2bf(float f){
  __bf16 h = (__bf16)f;
  return __builtin_bit_cast(u16, h);
}
// async global->LDS, 16B per lane; LDS dest = wave-uniform base + lane*16 (m104/m108)
__device__ __forceinline__ void async_copy16(const void* g, void* l){
  __builtin_amdgcn_global_load_lds((const __attribute__((address_space(1))) u32*)g,
                                   (__attribute__((address_space(3))) u32*)l, 16, 0, 0);
}
template<int N> __device__ __forceinline__ void wait_vm(){
  if constexpr (N==8)      asm volatile("s_waitcnt vmcnt(8)" ::: "memory");
  else if constexpr (N==6) asm volatile("s_waitcnt vmcnt(6)" ::: "memory");
  else if constexpr (N==4) asm volatile("s_waitcnt vmcnt(4)" ::: "memory");
  else if constexpr (N==3) asm volatile("s_waitcnt vmcnt(3)" ::: "memory");
  else                     asm volatile("s_waitcnt vmcnt(0)" ::: "memory");
}
__device__ __forceinline__ void barrier_pin(){
  asm volatile("s_barrier" ::: "memory");
  __builtin_amdgcn_sched_barrier(0);      // pin phases: no MFMA/read drift across (rule #18)
}

// ---------------- fp32 -> bf16 convert (4 elems/thread) ----------------
__global__ __launch_bounds__(256)
void kcvt(const float* __restrict__ src, u16* __restrict__ dst, long n){
  const long i = ((long)blockIdx.x * 256 + threadIdx.x) * 4;
  if (i + 3 >= n) {
    for (long j = i; j < n; j++) dst[j] = f2bf(src[j]);
    return;
  }
  const float4 v = *(const float4*)&src[i];
  u16x4 o; o.x = f2bf(v.x); o.y = f2bf(v.y); o.z = f2bf(v.z); o.w = f2bf(v.w);
  *(u16x4*)&dst[i] = o;
}

// ---------------- fp32 read, transpose, bf16 write; 32x32 tiles ----------------
__global__ __launch_bounds__(256)
void ktranspose_cvt(const float* __restrict__ src, u16* __restrict__ dst, int R, int C){
  __shared__ u16 tile[32][33];
  const int tx = threadIdx.x & 31, ty = threadIdx.x >> 5;   // 32 x 8
  const long bx = (long)blockIdx.x * 32, by = (long)blockIdx.y * 32;
  #pragma unroll
  for (int i = 0; i < 32; i += 8) tile[ty + i][tx] = f2bf(src[(by + ty + i) * C + bx + tx]);
  __syncthreads();
  #pragma unroll
  for (int i = 0; i < 32; i += 8) dst[(bx + ty + i) * R + by + tx] = tile[tx][ty + i];
}

// ---------------- gemm8p: 256xBN tile, BK=32, 8 waves, 2 fine phases/tile, 4-buf pipeline ----
// Per phase: {ds_read frags; stage 1 half-tile of tile j+3; s_barrier; setprio(1); MFMA x16/8;
// setprio(0); [tile end: counted vmcnt BEFORE closing barrier]; s_barrier}.
// 8 phases per K=128 (m201 density). vmcnt never drains to 0 in steady state (T4).
// WAR-safe by construction: stage(j+3) -> buf[(j+3)&3]; its previous tenant j-1 was fully
// consumed before tile j-1's closing barrier, which precedes this stage's issue.
// EPI==0 (BN=256): scatter bf16 into Q [BH,L,64], K [BH,L,64], VT [BH,64,L]
// EPI==1 (BN=128): OF[m*1024 + n] = fp32(acc + bias)
template<int EPI, int BN>
__global__ __launch_bounds__(512, 2)
void gemm8p(const u16* __restrict__ A, const u16* __restrict__ BT, const float* __restrict__ bias,
            u16* __restrict__ O0, u16* __restrict__ O1, u16* __restrict__ O2,
            float* __restrict__ OF)
{
  constexpr int K = 1024, NT = K / 32;           // 32 K-tiles
  constexpr int NF = BN / 64;                    // B-frags per wave: 4 or 2
  constexpr int BUFSZ = 16384 + BN * 64;         // A 16KB + B (16KB or 8KB)
  constexpr int PT = 2 + BN / 128;               // vmem insts per tile: 4 or 3
  extern __shared__ __align__(16) char lds[];    // 4 * BUFSZ
  const int t = threadIdx.x, lane = t & 63, wave = t >> 6;
  const int quad = lane >> 4, l15 = lane & 15;

  // T1: XCD-aware bijective swizzle (nwg % 8 == 0: 384 and 256)
  const int nwgx = gridDim.x;
  const int nwg = nwgx * gridDim.y;
  int bid = blockIdx.y * nwgx + blockIdx.x;
  bid = (bid & 7) * (nwg >> 3) + (bid >> 3);
  const int m0 = (bid / nwgx) * 256, n0 = (bid % nwgx) * BN;

  const int wm = (wave >> 2) * 128, wn = (wave & 3) * (BN / 4);

  // staging source (inverse T2 granule swizzle on global source; rule 21)
  const int srow = t >> 2;                                  // 0..127
  const int sg   = (t & 3) ^ ((srow >> 1) & 3);             // logical granule at phys slot t&3
  const long aofs0 = (long)min(m0 + srow,       MM - 1) * K + sg * 8;
  const long aofs1 = (long)min(m0 + srow + 128, MM - 1) * K + sg * 8;
  const long bofs0 = (long)(n0 + srow) * K + sg * 8;
  const long bofs1 = (long)(n0 + srow + 128) * K + sg * 8;  // unused when BN==128

  // ds_read byte offsets (T2 swizzle on read side; measured 0-conflict round 1)
  const int swz = (l15 >> 1) & 3;
  int aoff[8], boff[NF];
  #pragma unroll
  for (int m = 0; m < 8; m++)  aoff[m] = (wm + m * 16 + l15) * 64 + ((quad ^ swz) << 4);
  #pragma unroll
  for (int n = 0; n < NF; n++) boff[n] = 16384 + (wn + n * 16 + l15) * 64 + ((quad ^ swz) << 4);

  f32x4 acc[8][NF] = {};

  auto STAGE_A = [&](int j){
    char* d = lds + (j & 3) * BUFSZ + wave * 1024;
    const long kt = (long)j * 32;
    async_copy16(A + aofs0 + kt, d);
    async_copy16(A + aofs1 + kt, d + 8192);
  };
  auto STAGE_B = [&](int j){
    char* d = lds + (j & 3) * BUFSZ + 16384 + wave * 1024;
    const long kt = (long)j * 32;
    async_copy16(BT + bofs0 + kt, d);
    if constexpr (BN == 256) async_copy16(BT + bofs1 + kt, d + 8192);
  };

  // prologue: tiles 0,1,2 staged (3*PT insts); wait tile 0, keep tiles 1,2 in flight
  STAGE_A(0); STAGE_B(0);
  STAGE_A(1); STAGE_B(1);
  STAGE_A(2); STAGE_B(2);
  wait_vm<2 * PT>();
  barrier_pin();

  for (int j = 0; j < NT; ++j) {
    char* buf = lds + (j & 3) * BUFSZ;
    // ---- phase A: B-frags + A-frags[0..3], stage A(j+3), 16/8 MFMA ----
    bf16x8 bfr[NF], afr[4];
    #pragma unroll
    for (int n = 0; n < NF; n++) bfr[n] = *(const bf16x8*)(buf + boff[n]);
    #pragma unroll
    for (int m = 0; m < 4; m++)  afr[m] = *(const bf16x8*)(buf + aoff[m]);
    if (j + 3 < NT) STAGE_A(j + 3);
    barrier_pin();
    __builtin_amdgcn_s_setprio(1);
    #pragma unroll
    for (int m = 0; m < 4; m++)
      #pragma unroll
      for (int n = 0; n < NF; n++)
        acc[m][n] = __builtin_amdgcn_mfma_f32_16x16x32_bf16(afr[m], bfr[n], acc[m][n], 0, 0, 0);
    __builtin_amdgcn_s_setprio(0);
    barrier_pin();
    // ---- phase B: A-frags[4..7] (B reused in regs), stage B(j+3), 16/8 MFMA ----
    #pragma unroll
    for (int m = 0; m < 4; m++)  afr[m] = *(const bf16x8*)(buf + aoff[4 + m]);
    if (j + 3 < NT) STAGE_B(j + 3);
    barrier_pin();
    __builtin_amdgcn_s_setprio(1);
    #pragma unroll
    for (int m = 0; m < 4; m++)
      #pragma unroll
      for (int n = 0; n < NF; n++)
        acc[4 + m][n] = __builtin_amdgcn_mfma_f32_16x16x32_bf16(afr[m], bfr[n], acc[4 + m][n], 0, 0, 0);
    __builtin_amdgcn_s_setprio(0);
    // counted vmcnt BEFORE the tile's closing barrier (barrier = all-waves-ready fence).
    if (j <= NT - 4)      wait_vm<2 * PT>();   // tiles j+2, j+3 stay in flight
    else if (j == NT - 3) wait_vm<PT>();       // tile j+2 in flight
    else if (j == NT - 2) wait_vm<0>();        // last tile must be complete
    barrier_pin();
  }

  // ---------------- epilogue (unchanged semantics, validated rounds 0-1) ----------------
  float bs[NF]; int cols[NF];
  #pragma unroll
  for (int n = 0; n < NF; n++) { cols[n] = n0 + wn + n * 16 + l15; bs[n] = bias[cols[n]]; }

  #pragma unroll
  for (int m = 0; m < 8; m++) {
    #pragma unroll
    for (int r = 0; r < 4; r++) {
      const int row = m0 + wm + m * 16 + quad * 4 + r;  // C/D: row = quad*4+reg, col = lane&15 (m89)
      if (row >= MM) continue;
      if (EPI == 0) {
        const int b = row / 1000, l = row - b * 1000;
        #pragma unroll
        for (int n = 0; n < NF; n++) {
          const u16 o = f2bf(acc[m][n][r] + bs[n]);
          const int col = cols[n];
          const int which = col >> 10, hh = (col >> 6) & 15, dd = col & 63;
          const int bh = b * 16 + hh;
          if      (which == 0) O0[((long)bh * LQ + l) * 64 + dd] = o;
          else if (which == 1) O1[((long)bh * LQ + l) * 64 + dd] = o;
          else                 O2[((long)bh * 64 + dd) * LQ + l] = o;   // V stored transposed per head
        }
      } else {
        #pragma unroll
        for (int n = 0; n < NF; n++)
          OF[(long)row * 1024 + cols[n]] = acc[m][n][r] + bs[n];        // fp32 store
      }
    }
  }
}

// ---------------- flash attention v4: balanced pairing + register prefetch (r9, validated) ----------
__global__ __launch_bounds__(256)
void attn_kernel(const u16* __restrict__ Qb, const u16* __restrict__ Kb,
                 const u16* __restrict__ VTb, u16* __restrict__ AO)
{
  __shared__ __align__(16) u16 Ps[4][2][16 * 40];   // [wave][qblock][q=16][key=32 +8 pad]
  const int t = threadIdx.x, lane = t & 63, wave = t >> 6;
  const int quad = lane >> 4, l15 = lane & 15;
  const int bh = blockIdx.y;
  const int c = blockIdx.x * 4 + wave;              // 0..15 (grid.x = 4)
  const u16* Q  = Qb  + (long)bh * LQ * 64;
  const u16* Kp = Kb  + (long)bh * LQ * 64;
  const u16* VT = VTb + (long)bh * 64 * LQ;
  const int b = bh >> 4, h = bh & 15;
  const float sscale = 0.18033688011112042f;        // (1/sqrt(64)) * log2(e)

  for (int pass = 0; pass < 2; ++pass) {
    const int chunk = pass ? (31 - c) : c;          // pass0: 0..15, pass1: 16..31
    const int qbase = chunk * 32;
    const int nkt = chunk + 1;

    // Q B-frags for the two 16-col q-blocks: B[k=d=quad*8+j][n=q=l15]
    int qv[2]; bf16x8 bq0[2], bq1[2];
    #pragma unroll
    for (int g = 0; g < 2; g++) {
      qv[g] = qbase + g * 16 + l15;
      const int qc = min(qv[g], LQ - 1);
      bq0[g] = *(const bf16x8*)&Q[(long)qc * 64 +      quad * 8];
      bq1[g] = *(const bf16x8*)&Q[(long)qc * 64 + 32 + quad * 8];
    }

    float l_p[2] = { 0.f, 0.f };
    f32x4 o[2][4] = {};

    // prefetch tile 0
    bf16x8 pa00, pa01, pa10, pa11, pav0, pav1, pav2, pav3;
    {
      const int krA = min(l15, LQ - 1), krB = min(16 + l15, LQ - 1);
      pa00 = *(const bf16x8*)&Kp[(long)krA * 64 +      quad * 8];
      pa01 = *(const bf16x8*)&Kp[(long)krA * 64 + 32 + quad * 8];
      pa10 = *(const bf16x8*)&Kp[(long)krB * 64 +      quad * 8];
      pa11 = *(const bf16x8*)&Kp[(long)krB * 64 + 32 + quad * 8];
      const int vcol = min(quad * 8, LQ - 8);
      pav0 = *(const bf16x8*)&VT[(long)( 0 + l15) * LQ + vcol];
      pav1 = *(const bf16x8*)&VT[(long)(16 + l15) * LQ + vcol];
      pav2 = *(const bf16x8*)&VT[(long)(32 + l15) * LQ + vcol];
      pav3 = *(const bf16x8*)&VT[(long)(48 + l15) * LQ + vcol];
    }

    for (int kk = 0; kk < nkt; ++kk) {
      const int k0 = kk * 32;
      const bool lastt = (kk + 1 == nkt);           // wave-uniform
      const bf16x8 a00 = pa00, a01 = pa01, a10 = pa10, a11 = pa11;
      bf16x8 av[4] = { pav0, pav1, pav2, pav3 };
      if (!lastt) {                                 // issue next tile's loads early
        const int n0k = k0 + 32;
        const int krA = min(n0k + l15, LQ - 1), krB = min(n0k + 16 + l15, LQ - 1);
        pa00 = *(const bf16x8*)&Kp[(long)krA * 64 +      quad * 8];
        pa01 = *(const bf16x8*)&Kp[(long)krA * 64 + 32 + quad * 8];
        pa10 = *(const bf16x8*)&Kp[(long)krB * 64 +      quad * 8];
        pa11 = *(const bf16x8*)&Kp[(long)krB * 64 + 32 + quad * 8];
        const int vcol = min(n0k + quad * 8, LQ - 8);
        pav0 = *(const bf16x8*)&VT[(long)( 0 + l15) * LQ + vcol];
        pav1 = *(const bf16x8*)&VT[(long)(16 + l15) * LQ + vcol];
        pav2 = *(const bf16x8*)&VT[(long)(32 + l15) * LQ + vcol];
        pav3 = *(const bf16x8*)&VT[(long)(48 + l15) * LQ + vcol];
      }

      #pragma unroll
      for (int g = 0; g < 2; g++) {
        const f32x4 z = {};
        f32x4 s0 = __builtin_amdgcn_mfma_f32_16x16x32_bf16(a00, bq0[g], z, 0, 0, 0);
        s0       = __builtin_amdgcn_mfma_f32_16x16x32_bf16(a01, bq1[g], s0, 0, 0, 0);
        f32x4 s1 = __builtin_amdgcn_mfma_f32_16x16x32_bf16(a10, bq0[g], z, 0, 0, 0);
        s1       = __builtin_amdgcn_mfma_f32_16x16x32_bf16(a11, bq1[g], s1, 0, 0, 0);

        float p0[4], p1[4];
        if (lastt) {                                // only masked tile (k0 == qbase)
          const int q = qv[g];
          #pragma unroll
          for (int r = 0; r < 4; r++) {
            const int key0 = k0 + quad * 4 + r;     // S^T row = key (m89)
            p0[r] = __builtin_amdgcn_exp2f((key0      <= q) ? s0[r] * sscale : -3.0e38f);
            p1[r] = __builtin_amdgcn_exp2f((key0 + 16 <= q) ? s1[r] * sscale : -3.0e38f);
          }
        } else {
          #pragma unroll
          for (int r = 0; r < 4; r++) {
            p0[r] = __builtin_amdgcn_exp2f(s0[r] * sscale);
            p1[r] = __builtin_amdgcn_exp2f(s1[r] * sscale);
          }
        }
        u16x4 w0, w1; float ls = 0.f;
        #pragma unroll
        for (int r = 0; r < 4; r++) {
          w0[r] = f2bf(p0[r]); w1[r] = f2bf(p1[r]);
          ls += p0[r] + p1[r];
        }
        l_p[g] += ls;
        // P[q][key] -> per-wave LDS (same-wave write->read, proven safe rounds 2-9)
        *(u16x4*)&Ps[wave][g][l15 * 40 + quad * 4]      = w0;
        *(u16x4*)&Ps[wave][g][l15 * 40 + 16 + quad * 4] = w1;
        // B-frag of P^T: B[k=key=quad*8+j][n=q=l15]
        const bf16x8 bp = *(const bf16x8*)&Ps[wave][g][l15 * 40 + quad * 8];
        #pragma unroll
        for (int cc = 0; cc < 4; cc++)
          o[g][cc] = __builtin_amdgcn_mfma_f32_16x16x32_bf16(av[cc], bp, o[g][cc], 0, 0, 0);
      }
    }

    #pragma unroll
    for (int g = 0; g < 2; g++) {
      if (qv[g] >= LQ) continue;
      float l = l_p[g];                             // cross-quad reduce once per chunk
      l += __shfl_xor(l, 16);
      l += __shfl_xor(l, 32);
      const float inv = 1.0f / l;
      const long base = ((long)(b * LQ + qv[g])) * 1024 + h * 64;
      #pragma unroll
      for (int cc = 0; cc < 4; cc++) {              // O^T: row d = cc*16+quad*4+r, col q
        u16x4 w;
        #pragma unroll
        for (int r = 0; r < 4; r++) w[r] = f2bf(o[g][cc][r] * inv);
        *(u16x4*)&AO[base + cc * 16 + quad * 4] = w; // 8B store, d-contiguous
      }
    }
  }
}

// ---------------- launcher ----------------
extern "C" void kernel_launch(void* const* d_in, const int* in_sizes, int n_in,
                              void* d_out, int out_size, void* d_ws, size_t ws_size,
                              hipStream_t stream) {
  const float* x    = (const float*)d_in[0];   // [8,1000,1024] fp32
  const float* Wqkv = (const float*)d_in[1];   // [1024,3072]  fp32
  const float* bqkv = (const float*)d_in[2];   // [3072]       fp32
  const float* Wo   = (const float*)d_in[3];   // [1024,1024]  fp32
  const float* bo   = (const float*)d_in[4];   // [1024]       fp32
  float* out = (float*)d_out;                  // [8,1000,1024] fp32

  char* ws = (char*)d_ws;                      // validated layout (rounds 2-9)
  u16* WqkvT = (u16*)(ws);                                   // 3072*1024*2 = 6291456
  u16* WoT   = (u16*)(ws + 6291456);                         // 1024*1024*2 = 2097152
  u16* xb    = (u16*)(ws + 8388608);                         // 8000*1024*2 = 16384000
  u16* Qb    = (u16*)(ws + 8388608 + 16384000L);             // 128*1000*64*2
  u16* Kb    = (u16*)(ws + 8388608 + 2 * 16384000L);
  u16* VTb   = (u16*)(ws + 8388608 + 3 * 16384000L);
  u16* AO    = xb;   // reuse: x fully consumed by gemm<0> before attn writes AO

  static bool inited = false;                  // allow large dynamic LDS (one-time)
  if (!inited) {
    (void)hipFuncSetAttribute(reinterpret_cast<const void*>(&gemm8p<0, 256>),
                              hipFuncAttributeMaxDynamicSharedMemorySize, 131072);
    (void)hipFuncSetAttribute(reinterpret_cast<const void*>(&gemm8p<1, 128>),
                              hipFuncAttributeMaxDynamicSharedMemorySize, 98304);
    inited = true;
  }

  kcvt<<<8000, 256, 0, stream>>>(x, xb, 8192000L);
  ktranspose_cvt<<<dim3(96, 32), 256, 0, stream>>>(Wqkv, WqkvT, 1024, 3072);
  ktranspose_cvt<<<dim3(32, 32), 256, 0, stream>>>(Wo,   WoT,   1024, 1024);
  gemm8p<0, 256><<<dim3(12, 32), 512, 131072, stream>>>(xb, WqkvT, bqkv, Qb, Kb, VTb, nullptr);
  attn_kernel<<<dim3(4, 128), 256, 0, stream>>>(Qb, Kb, VTb, AO);
  gemm8p<1, 128><<<dim3(8, 32), 512, 98304, stream>>>(AO, WoT, bo, nullptr, nullptr, nullptr, out);
}